// Round 3
// baseline (675.534 us; speedup 1.0000x reference)
//
#include <hip/hip_runtime.h>

// out[i][j] = (sd[i][j] < 5 ? 1 : 0)
//           * (lbl[i]==lbl[j] ? 1.0 : 0.1)
//           * exp(-(sd^2 + dtw^2))        // fused: exp(-sd^2)*exp(-dtw^2)
//
// N = 8192, float32. adj_mx (d_in[0]) is unused by the reference -> never read.
//
// V4 = V3 (block-contiguous batch-of-4) but with the MLP FORCED into codegen:
// V3 compiled to VGPR_Count=28 -> the compiler sank the 8 float4 loads back
// into their uses (can't hold 32 result VGPRs in a 28-reg budget), so only
// ~2-3 loads were ever in flight and dur didn't move (189->185us).
//   - __launch_bounds__(256, 6): relax VGPR cap (target ~24 waves/CU, which
//     is what we measure anyway at 80% occupancy) so 8 results fit.
//   - sched_barrier(0) after the load cluster: forbid sinking loads.
//   - label loads issued FIRST: vmcnt retires in issue order, so the first
//     item's compute waits at vmcnt(6) instead of vmcnt(0) -> pipelined drain.

#define N_DIM 8192
#define DTW_DELTA 5.0f
#define EPS_CLU 0.1f

typedef float f4  __attribute__((ext_vector_type(4)));
typedef int   i4v __attribute__((ext_vector_type(4)));

__device__ __forceinline__ f4 calc(f4 s, f4 d, int li, i4v lj)
{
    f4 o;
#pragma unroll
    for (int k = 0; k < 4; ++k) {
        float g = __expf(-(s[k] * s[k] + d[k] * d[k]));
        float v = (li == lj[k]) ? g : EPS_CLU * g;
        o[k] = (s[k] < DTW_DELTA) ? v : 0.0f;
    }
    return o;
}

__global__ __launch_bounds__(256, 6) void dtw_mask_kernel(
    const f4*  __restrict__ sd4,
    const f4*  __restrict__ dtw4,
    const int* __restrict__ lbl,
    f4*        __restrict__ out4)
{
    // Each block owns 1024 consecutive float4s: items at base + k*256.
    // 16384 blocks x 1024 = 16,777,216 float4s = 8192*8192 floats. No tail.
    const long long base = (long long)blockIdx.x * 1024 + threadIdx.x;
    const long long i0 = base;
    const long long i1 = base + 256;
    const long long i2 = base + 512;
    const long long i3 = base + 768;

    const i4v* __restrict__ lbl4 = (const i4v*)lbl;
    const int m = N_DIM / 4 - 1;

    // ---- cheap cache-resident loads first (issue-order = vmcnt order) ----
    // row = float4idx >> 11; 1024 | 2048 so the row is block-uniform.
    const int li  = lbl[(int)(base >> 11)];
    i4v lj0 = lbl4[(int)(i0 & m)];
    i4v lj1 = lbl4[(int)(i1 & m)];
    i4v lj2 = lbl4[(int)(i2 & m)];
    i4v lj3 = lbl4[(int)(i3 & m)];

    // ---- all 8 HBM loads issued before any use ----
    f4 s0 = sd4[i0];
    f4 d0 = dtw4[i0];
    f4 s1 = sd4[i1];
    f4 d1 = dtw4[i1];
    f4 s2 = sd4[i2];
    f4 d2 = dtw4[i2];
    f4 s3 = sd4[i3];
    f4 d3 = dtw4[i3];

    // Scheduler fence: nothing (esp. the loads above) may cross this point,
    // so the compiler cannot sink loads into their uses to save registers.
    __builtin_amdgcn_sched_barrier(0);

    // Compute/store in issue order: o0 can start at vmcnt(6) (s1..d3 still
    // outstanding), o1 at vmcnt(4), etc. -> overlapped drain.
    out4[i0] = calc(s0, d0, li, lj0);
    out4[i1] = calc(s1, d1, li, lj1);
    out4[i2] = calc(s2, d2, li, lj2);
    out4[i3] = calc(s3, d3, li, lj3);
}

extern "C" void kernel_launch(void* const* d_in, const int* in_sizes, int n_in,
                              void* d_out, int out_size, void* d_ws, size_t ws_size,
                              hipStream_t stream)
{
    // setup_inputs order: adj_mx, sd_mx, dtw_matrix, cluster_labels
    const f4*  sd  = (const f4*)d_in[1];
    const f4*  dtw = (const f4*)d_in[2];
    const int* lbl = (const int*)d_in[3];
    f4* out = (f4*)d_out;

    const long long nvec = (long long)N_DIM * N_DIM / 4;   // 16,777,216
    const int block = 256;
    const int items_per_block = block * 4;                 // 1024 float4s
    int grid = (int)((nvec + items_per_block - 1) / items_per_block); // 16384
    dtw_mask_kernel<<<grid, block, 0, stream>>>(sd, dtw, lbl, out);
}